// Round 15
// baseline (367.079 us; speedup 1.0000x reference)
//
#include <hip/hip_runtime.h>
#include <hip/hip_bf16.h>
#include <hip/hip_fp16.h>
#include <stdint.h>

#define TPB 256
#define EPSF 1e-5f

using i32x4  = __attribute__((ext_vector_type(4))) int;
using i32x16 = __attribute__((ext_vector_type(16))) int;

// ---------------- helpers ----------------

__device__ __forceinline__ void gload16(const void* g, void* l) {
    __builtin_amdgcn_global_load_lds(
        (__attribute__((address_space(1))) void*)g,
        (__attribute__((address_space(3))) void*)l,
        16, 0, 0);
}

__device__ __forceinline__ float wave_reduce_sum(float v) {
#pragma unroll
    for (int off = 32; off > 0; off >>= 1) v += __shfl_down(v, off, 64);
    return v;
}

__device__ __forceinline__ float wave_reduce_max(float v) {
#pragma unroll
    for (int off = 32; off > 0; off >>= 1) v = fmaxf(v, __shfl_down(v, off, 64));
    return v;
}

__device__ __forceinline__ int q8(float f, float scale, float lo, float hi) {
    return (int)fminf(fmaxf(rintf(f * scale), lo), hi);
}

// fast GELU: x * sigmoid(2*u), u = sqrt(2/pi)*(x + 0.044715 x^3)
__device__ __forceinline__ float gelu_fast(float x) {
    float x2 = x * x;
    float u = x * (0.7978845608f + 0.0356774081f * x2);
    float e = exp2f(u * -2.8853900817779268f);   // exp(-2u)
    return x * __builtin_amdgcn_rcpf(1.0f + e);
}

// ---------------- scale reduction (deterministic two-pass) ----------------

__global__ void abssum2(const float* __restrict__ w1, const float* __restrict__ w2,
                        int n4, float* __restrict__ part) {
    const bool second = blockIdx.x >= 2048;
    const float4* w4 = (const float4*)(second ? w2 : w1);
    const int b = blockIdx.x & 2047;
    float acc = 0.f;
    for (int i = b * TPB + threadIdx.x; i < n4; i += 2048 * TPB) {
        float4 v = w4[i];
        acc += fabsf(v.x) + fabsf(v.y) + fabsf(v.z) + fabsf(v.w);
    }
    acc = wave_reduce_sum(acc);
    __shared__ float sh[4];
    if ((threadIdx.x & 63) == 0) sh[threadIdx.x >> 6] = acc;
    __syncthreads();
    if (threadIdx.x == 0) part[blockIdx.x] = sh[0] + sh[1] + sh[2] + sh[3];
}

__global__ void finalize_scales(const float* __restrict__ part,
                                float* __restrict__ scales, float inv_n) {
    float a = 0.f, b = 0.f;
    for (int i = threadIdx.x; i < 2048; i += TPB) { a += part[i]; b += part[i + 2048]; }
    a = wave_reduce_sum(a);
    b = wave_reduce_sum(b);
    __shared__ float sa[4], sb[4];
    if ((threadIdx.x & 63) == 0) { sa[threadIdx.x >> 6] = a; sb[threadIdx.x >> 6] = b; }
    __syncthreads();
    if (threadIdx.x == 0) {
        scales[0] = fmaxf((sa[0] + sa[1] + sa[2] + sa[3]) * inv_n, EPSF);
        scales[1] = fmaxf((sb[0] + sb[1] + sb[2] + sb[3]) * inv_n, EPSF);
    }
}

// ---------------- weight ternarization -> int8 (natural K order, for w1) -----

__global__ void quant_w_i8(const float* __restrict__ w,
                           signed char* __restrict__ wq,
                           const float* __restrict__ scales, int sidx, int n4) {
    const float inv = 1.0f / scales[sidx];
    const float4* w4 = (const float4*)w;
    unsigned* oq = (unsigned*)wq;
    for (int i = blockIdx.x * TPB + threadIdx.x; i < n4; i += gridDim.x * TPB) {
        float4 v = w4[i];
        unsigned p = ((unsigned)(q8(v.x, inv, -1.f, 1.f) & 0xff)) |
                     ((unsigned)(q8(v.y, inv, -1.f, 1.f) & 0xff) << 8) |
                     ((unsigned)(q8(v.z, inv, -1.f, 1.f) & 0xff) << 16) |
                     ((unsigned)(q8(v.w, inv, -1.f, 1.f) & 0xff) << 24);
        oq[i] = p;
    }
}

// ---------------- w2 ternarization with within-64 K-permutation -------------
// pi(c) = 4*(c&15) + ((c>>4)&3) within each 64-aligned K group; h/hq share pi.
// Shape-invariant for GEMM2: both MFMA operands read identical stored
// positions, so any within-64 bijection cancels in the dot product.

__global__ void quant_w2_i8perm(const float* __restrict__ w,
                                signed char* __restrict__ wq,
                                const float* __restrict__ scales, int n4) {
    const float inv = 1.0f / scales[1];
    const float4* w4 = (const float4*)w;
    unsigned* oq = (unsigned*)wq;
    const int t = threadIdx.x;
    const int g = t & 15;
    const int srcbase = (t & ~15);
    for (int i = blockIdx.x * TPB + t; i < n4; i += gridDim.x * TPB) {
        float4 v = w4[i];
        unsigned p = ((unsigned)(q8(v.x, inv, -1.f, 1.f) & 0xff)) |
                     ((unsigned)(q8(v.y, inv, -1.f, 1.f) & 0xff) << 8) |
                     ((unsigned)(q8(v.z, inv, -1.f, 1.f) & 0xff) << 16) |
                     ((unsigned)(q8(v.w, inv, -1.f, 1.f) & 0xff) << 24);
        unsigned out = 0;
#pragma unroll
        for (int j = 0; j < 4; ++j) {
            unsigned pj = (unsigned)__shfl((int)p, srcbase + 4 * j + (g >> 2), 64);
            out |= ((pj >> ((g & 3) * 8)) & 0xffu) << (8 * j);
        }
        oq[i] = out;
    }
}

// ---------------- per-row activation quant: fp32 -> int8 ----------------

template <int NF4>
__global__ void quant_x_i8(const float* __restrict__ in,
                           signed char* __restrict__ outq,
                           float* __restrict__ dq, int cols) {
    const long long row = blockIdx.x;
    const float4* r4 = (const float4*)(in + row * (long long)cols);
    float4 v[NF4];
    float mx = 0.f;
#pragma unroll
    for (int j = 0; j < NF4; ++j) {
        v[j] = r4[threadIdx.x + TPB * j];
        mx = fmaxf(mx, fmaxf(fmaxf(fabsf(v[j].x), fabsf(v[j].y)),
                             fmaxf(fabsf(v[j].z), fabsf(v[j].w))));
    }
    mx = wave_reduce_max(mx);
    __shared__ float sh[4];
    __shared__ float res;
    if ((threadIdx.x & 63) == 0) sh[threadIdx.x >> 6] = mx;
    __syncthreads();
    if (threadIdx.x == 0) res = fmaxf(fmaxf(sh[0], sh[1]), fmaxf(sh[2], sh[3]));
    __syncthreads();
    const float clipped = fmaxf(res, EPSF);
    const float scale = 127.f / clipped;
    if (threadIdx.x == 0) dq[row] = clipped / 127.f;
    unsigned* oq = (unsigned*)(outq + row * (long long)cols);
#pragma unroll
    for (int j = 0; j < NF4; ++j) {
        unsigned p = ((unsigned)(q8(v[j].x, scale, -128.f, 127.f) & 0xff)) |
                     ((unsigned)(q8(v[j].y, scale, -128.f, 127.f) & 0xff) << 8) |
                     ((unsigned)(q8(v[j].z, scale, -128.f, 127.f) & 0xff) << 16) |
                     ((unsigned)(q8(v[j].w, scale, -128.f, 127.f) & 0xff) << 24);
        oq[threadIdx.x + TPB * j] = p;
    }
}

// ---------------- per-row quant: fp16 (pre-gelu) -> gelu -> int8 ------------

template <int NJ>
__global__ void quant_h_i8(const unsigned short* __restrict__ h,
                           signed char* __restrict__ outq,
                           float* __restrict__ dq, int cols) {
    const long long row = blockIdx.x;
    const unsigned short* rp = h + row * (long long)cols;
    float g[NJ * 8];
    float mx = 0.f;
#pragma unroll
    for (int j = 0; j < NJ; ++j) {
        uint4 v = *(const uint4*)(rp + (threadIdx.x + TPB * j) * 8);
        const unsigned* u = (const unsigned*)&v;
#pragma unroll
        for (int e = 0; e < 4; ++e) {
            float2 f2 = __half22float2(*(const __half2*)&u[e]);
            float g0 = gelu_fast(f2.x);
            float g1 = gelu_fast(f2.y);
            g[j * 8 + 2 * e] = g0;
            g[j * 8 + 2 * e + 1] = g1;
            mx = fmaxf(mx, fmaxf(fabsf(g0), fabsf(g1)));
        }
    }
    mx = wave_reduce_max(mx);
    __shared__ float sh[4];
    __shared__ float res;
    if ((threadIdx.x & 63) == 0) sh[threadIdx.x >> 6] = mx;
    __syncthreads();
    if (threadIdx.x == 0) res = fmaxf(fmaxf(sh[0], sh[1]), fmaxf(sh[2], sh[3]));
    __syncthreads();
    const float clipped = fmaxf(res, EPSF);
    const float scale = 127.f / clipped;
    if (threadIdx.x == 0) dq[row] = clipped / 127.f;
    uint2* oq = (uint2*)(outq + row * (long long)cols);
#pragma unroll
    for (int j = 0; j < NJ; ++j) {
        unsigned o[2] = {0, 0};
#pragma unroll
        for (int e = 0; e < 8; ++e) {
            unsigned b = (unsigned)(q8(g[j * 8 + e], scale, -128.f, 127.f) & 0xff);
            o[e >> 2] |= b << ((e & 3) * 8);
        }
        oq[threadIdx.x + TPB * j] = *(uint2*)o;
    }
}

// ---------------- shared GEMM pieces ----------------

__device__ __forceinline__ void stage_half(const char* Xb, long long rowB, int prow,
                                           int tk, char* dst, int tid, int cbs) {
    const long long gc = (long long)tk * 128 + cbs;
    const int r = tid >> 3;
    gload16(Xb + (long long)(prow + r) * rowB + gc, dst + tid * 16);
    gload16(Xb + (long long)(prow + 64 + r) * rowB + gc, dst + 8192 + tid * 16);
}

#define QUAD(MB, NB)                                                            \
    _Pragma("unroll") for (int mi = 0; mi < 4; ++mi)                            \
    _Pragma("unroll") for (int ni = 0; ni < 2; ++ni)                            \
    _Pragma("unroll") for (int ks = 0; ks < 2; ++ks)                            \
        acc[(MB)*4 + mi][(NB)*2 + ni] = __builtin_amdgcn_mfma_i32_16x16x64_i8(  \
            aq[mi][ks], bq[(NB)*2 + ni][ks], acc[(MB)*4 + mi][(NB)*2 + ni], 0, 0, 0);

#define READ_A(BUF, base_mi)                                                    \
    _Pragma("unroll") for (int mi = 0; mi < 4; ++mi) {                          \
        const char* p = (BUF) + aoff + ((mi + (base_mi)) * 16 + l15) * 128;     \
        aq[mi][0] = *(const i32x4*)(p + acb0);                                  \
        aq[mi][1] = *(const i32x4*)(p + acb1);                                  \
    }
#define READ_B(BUF, n0i, n1i)                                                   \
    _Pragma("unroll") for (int ni = (n0i); ni < (n1i); ++ni) {                  \
        const char* p = (BUF) + boff + (ni * 16 + l15) * 128;                   \
        bq[ni][0] = *(const i32x4*)(p + acb0);                                  \
        bq[ni][1] = *(const i32x4*)(p + acb1);                                  \
    }

#define LGKM(N) do { asm volatile("s_waitcnt lgkmcnt(" #N ")" ::: "memory");    \
                     __builtin_amdgcn_sched_barrier(0); } while (0)

// split epilogue for gemm1p: rows [MLO,MHI), NO gelu, pi-packed 8B stores
#define EMIT1(MLO, MHI, M0V)                                                    \
    _Pragma("unroll") for (int mi = (MLO); mi < (MHI); ++mi) {                  \
        _Pragma("unroll") for (int r = 0; r < 4; ++r) {                         \
            const long long m = (M0V) + wr * 128 + mi * 16 + l4 * 4 + r;        \
            const float f = dq[m] * s;                                          \
            __half2 lo = __floats2half2_rn((float)acc[mi][0][r] * f,            \
                                           (float)acc[mi][1][r] * f);           \
            __half2 hi = __floats2half2_rn((float)acc[mi][2][r] * f,            \
                                           (float)acc[mi][3][r] * f);           \
            uint2 pk;                                                           \
            pk.x = *(const unsigned*)&lo;                                       \
            pk.y = *(const unsigned*)&hi;                                       \
            *(uint2*)(C + m * (long long)N + n0 + wc * 64 + l15 * 4) = pk;      \
            acc[mi][0][r] = 0; acc[mi][1][r] = 0;                               \
            acc[mi][2][r] = 0; acc[mi][3][r] = 0;                               \
        }                                                                       \
    }

// ---------------- persistent GEMM1: x@w1^T -> fp16 h' (pi layout) -----------
// R14 exact (16x16x64, read-ahead skeleton, thin epilogue).

__global__ __launch_bounds__(512, 2) void gemm1p(
    const signed char* __restrict__ A, const signed char* __restrict__ B,
    unsigned short* __restrict__ C, int N, int K,
    const float* __restrict__ dq, const float* __restrict__ scales, int ntile) {
    __shared__ __align__(16) char lds[131072];

    const int tid = threadIdx.x;
    const int lane = tid & 63;
    const int wid = tid >> 6;
    const int wr = wid >> 2;
    const int wc = wid & 3;

    const unsigned orig = blockIdx.y * gridDim.x + blockIdx.x;
    const unsigned xk = orig & 7, j = orig >> 3;
    const unsigned bx = xk * 4 + (j & 3);
    const unsigned byg = j >> 2;

    const int n0 = (int)bx * 256;
    const long long rb = (long long)K;
    const char* Ab = (const char*)A;
    const char* Bb = (const char*)B;

    const int NTT = ntile << 4;

    const int cbs = (((tid & 7) ^ ((tid >> 3) & 7)) << 4);
    const int l15 = lane & 15, l4 = lane >> 4;
    const int swz = (lane & 7) << 4;
    const int acb0 = (l4 * 16) ^ swz;
    const int acb1 = (64 + l4 * 16) ^ swz;
    const int aoff = wr * 16384;
    const int boff = 32768 + (wc >> 1) * 16384 + (wc & 1) * 8192;

    i32x4 acc[8][4] = {};
    i32x4 aq[4][2], bq[4][2];

    auto mrow = [&](int v) -> int { return ((int)byg * ntile + (v >> 4)) * 256; };

    stage_half(Bb, rb, n0, 0, lds + 32768, tid, cbs);
    stage_half(Bb, rb, n0 + 128, 0, lds + 32768 + 16384, tid, cbs);
    stage_half(Ab, rb, mrow(0), 0, lds + 0, tid, cbs);
    stage_half(Ab, rb, mrow(0) + 128, 0, lds + 16384, tid, cbs);
    stage_half(Bb, rb, n0, 1, lds + 65536 + 32768, tid, cbs);
    stage_half(Bb, rb, n0 + 128, 1, lds + 65536 + 32768 + 16384, tid, cbs);
    stage_half(Ab, rb, mrow(1), 1, lds + 65536, tid, cbs);
    asm volatile("s_waitcnt vmcnt(6)" ::: "memory");
    __builtin_amdgcn_sched_barrier(0);
    __builtin_amdgcn_s_barrier();
    READ_A(lds, 0);
    READ_B(lds, 0, 2);

    const float s = scales[0];

    for (int vt = 0; vt < NTT; ++vt) {
        char* cur = lds + ((vt & 1) << 16);
        char* nxt = lds + (((vt + 1) & 1) << 16);
        const bool s1 = (vt + 1) < NTT;
        const bool s2 = (vt + 2) < NTT;
        const int kk = vt & 15;
        const int k1 = (vt + 1) & 15;
        const int k2 = (vt + 2) & 15;

        // P0
        if (s1) stage_half(Ab, rb, mrow(vt + 1) + 128, k1, nxt + 16384, tid, cbs);
        READ_B(cur, 2, 4);
        if (kk == 0 && vt > 0) { EMIT1(4, 8, mrow(vt - 1)); }
        __builtin_amdgcn_s_barrier();
        LGKM(4);
        __builtin_amdgcn_s_setprio(1);
        QUAD(0, 0);
        __builtin_amdgcn_s_setprio(0);

        // P1
        __builtin_amdgcn_s_barrier();
        LGKM(0);
        __builtin_amdgcn_s_setprio(1);
        QUAD(0, 1);
        __builtin_amdgcn_s_setprio(0);

        // P2
        if (s2) {
            stage_half(Bb, rb, n0, k2, cur + 32768, tid, cbs);
            stage_half(Bb, rb, n0 + 128, k2, cur + 32768 + 16384, tid, cbs);
        }
        READ_A(cur, 4);
        if (kk == 15) { EMIT1(0, 4, mrow(vt)); }
        __builtin_amdgcn_s_barrier();
        LGKM(0);
        __builtin_amdgcn_s_setprio(1);
        QUAD(1, 0);
        __builtin_amdgcn_s_setprio(0);

        // P3
        if (s2) { asm volatile("s_waitcnt vmcnt(4)" ::: "memory"); }
        else    { asm volatile("s_waitcnt vmcnt(0)" ::: "memory"); }
        __builtin_amdgcn_sched_barrier(0);
        __builtin_amdgcn_s_barrier();
        if (s2) stage_half(Ab, rb, mrow(vt + 2), k2, cur, tid, cbs);
        __builtin_amdgcn_s_setprio(1);
        QUAD(1, 1);
        __builtin_amdgcn_s_setprio(0);
        if (s1) {
            READ_A(nxt, 0);
            READ_B(nxt, 0, 2);
        }
    }

    { EMIT1(4, 8, mrow(NTT - 1)); }
}

// ---------------- GEMM2: 32x32x32 i8, R9 skeleton ----------------
// Same staging/vmcnt/barrier ledger as the 16x16 version (per-phase read
// counts identical: P0=4, P2=8, end=12). Fragment geometry:
//  A: row = mt*32 + (lane&31), col byte = ks*32 + ((lane>>5)<<4), ^swz
//  C/D: col = lane&31, row = (reg&3) + 8*(reg>>2) + 4*(lane>>5)  [m74/m101]
// Epilogue fp32 nt-stores are 32-lane contiguous (coalesced).

#define READ_A32(BUF, base_mt)                                                  \
    _Pragma("unroll") for (int mi = 0; mi < 2; ++mi)                            \
    _Pragma("unroll") for (int ks = 0; ks < 4; ++ks)                            \
        aq[mi][ks] = *(const i32x4*)((BUF) + aoff +                             \
            (((base_mt) + mi) * 32 + l31) * 128 + acbk[ks]);

#define READ_B32(BUF, nt)                                                       \
    _Pragma("unroll") for (int ks = 0; ks < 4; ++ks)                            \
        bq[nt][ks] = *(const i32x4*)((BUF) + boff +                             \
            ((nt) * 32 + l31) * 128 + acbk[ks]);

#define QUAD32(MB, NB)                                                          \
    _Pragma("unroll") for (int mi = 0; mi < 2; ++mi)                            \
    _Pragma("unroll") for (int ks = 0; ks < 4; ++ks)                            \
        acc[(MB)*2 + mi][NB] = __builtin_amdgcn_mfma_i32_32x32x32_i8(           \
            aq[mi][ks], bq[NB][ks], acc[(MB)*2 + mi][NB], 0, 0, 0);

__global__ __launch_bounds__(512, 2) void gemm2k32(
    const signed char* __restrict__ A, const signed char* __restrict__ B,
    float* __restrict__ C, int N, int K,
    const float* __restrict__ dq, const float* __restrict__ scales) {
    __shared__ __align__(16) char lds[131072];

    const int tid = threadIdx.x;
    const int lane = tid & 63;
    const int wid = tid >> 6;
    const int wr = wid >> 2;
    const int wc = wid & 3;

    const unsigned gx = gridDim.x;
    unsigned lin = blockIdx.y * gx + blockIdx.x;
    const unsigned qq = (gx * gridDim.y) >> 3;
    lin = (lin & 7) * qq + (lin >> 3);
    const unsigned bx = lin % gx;
    const unsigned by = lin / gx;

    const long long M0 = (long long)by * 256;
    const long long N0 = (long long)bx * 256;
    const long long rb = (long long)K;
    const char* Ab = (const char*)A + M0 * rb;
    const char* Bb = (const char*)B + N0 * rb;
    const int nt = K >> 7;

    const int cbs = (((tid & 7) ^ ((tid >> 3) & 7)) << 4);
    const int l31 = lane & 31;
    const int swz = (lane & 7) << 4;
    const int hi16 = (lane >> 5) << 4;
    const int acbk[4] = { (0   + hi16) ^ swz, (32  + hi16) ^ swz,
                          (64  + hi16) ^ swz, (96  + hi16) ^ swz };
    const int aoff = wr * 16384;
    const int boff = 32768 + wc * 8192;

    i32x16 acc[4][2] = {};
    i32x4 aq[2][4], bq[2][4];

    stage_half(Bb, rb, 0,   0, lds + 32768,         tid, cbs);
    stage_half(Bb, rb, 128, 0, lds + 32768 + 16384, tid, cbs);
    stage_half(Ab, rb, 0,   0, lds + 0,             tid, cbs);
    stage_half(Ab, rb, 128, 0, lds + 16384,         tid, cbs);
    stage_half(Bb, rb, 0,   1, lds + 65536 + 32768,         tid, cbs);
    stage_half(Bb, rb, 128, 1, lds + 65536 + 32768 + 16384, tid, cbs);
    stage_half(Ab, rb, 0,   1, lds + 65536,                 tid, cbs);
    asm volatile("s_waitcnt vmcnt(6)" ::: "memory");
    __builtin_amdgcn_sched_barrier(0);
    __builtin_amdgcn_s_barrier();
    READ_A32(lds, 0);     // m-tiles 0-1 (8 ds reads)
    READ_B32(lds, 0);     // n-tile 0   (4 ds reads)

    for (int t = 0; t < nt; ++t) {
        char* cur = lds + ((t & 1) << 16);
        char* nxt = lds + (((t + 1) & 1) << 16);
        const bool s1 = (t + 1) < nt;
        const bool s2 = (t + 2) < nt;

        // P0: stage A1(t+1); read B n-tile 1; QUAD(0,0)
        if (s1) stage_half(Ab, rb, 128, t + 1, nxt + 16384, tid, cbs);
        READ_B32(cur, 1);
        __builtin_amdgcn_s_barrier();
        LGKM(4);           // drain aq(mt01)+bq(nt0); leave bq(nt1) in flight
        __builtin_amdgcn_s_setprio(1);
        QUAD32(0, 0);
        __builtin_amdgcn_s_setprio(0);

        // P1: QUAD(0,1)
        __builtin_amdgcn_s_barrier();
        LGKM(0);
        __builtin_amdgcn_s_setprio(1);
        QUAD32(0, 1);
        __builtin_amdgcn_s_setprio(0);

        // P2: stage B0+B1(t+2); read A m-tiles 2-3; QUAD(1,0)
        if (s2) {
            stage_half(Bb, rb, 0, t + 2, cur + 32768, tid, cbs);
            stage_half(Bb, rb, 128, t + 2, cur + 32768 + 16384, tid, cbs);
        }
        READ_A32(cur, 2);
        __builtin_amdgcn_s_barrier();
        LGKM(0);
        __builtin_amdgcn_s_setprio(1);
        QUAD32(1, 0);
        __builtin_amdgcn_s_setprio(0);

        // P3: vmcnt; barrier; stage A0(t+2); QUAD(1,1); read-ahead nxt
        if (s2) { asm volatile("s_waitcnt vmcnt(4)" ::: "memory"); }
        else    { asm volatile("s_waitcnt vmcnt(0)" ::: "memory"); }
        __builtin_amdgcn_sched_barrier(0);
        __builtin_amdgcn_s_barrier();
        if (s2) stage_half(Ab, rb, 0, t + 2, cur, tid, cbs);
        __builtin_amdgcn_s_setprio(1);
        QUAD32(1, 1);
        __builtin_amdgcn_s_setprio(0);
        if (s1) {
            READ_A32(nxt, 0);
            READ_B32(nxt, 0);
        }
    }

    // epilogue: col = lane&31 (coalesced), row = (reg&3)+8*(reg>>2)+4*(lane>>5)
    const float s = scales[1];
    const int rbase = 4 * (lane >> 5);
#pragma unroll
    for (int mt = 0; mt < 4; ++mt) {
#pragma unroll
        for (int ni = 0; ni < 2; ++ni) {
#pragma unroll
            for (int r = 0; r < 16; ++r) {
                const long long m = M0 + wr * 128 + mt * 32 +
                                    (r & 3) + 8 * (r >> 2) + rbase;
                const long long n = N0 + wc * 64 + ni * 32 + l31;
                __builtin_nontemporal_store(
                    (float)acc[mt][ni][r] * dq[m] * s, C + m * (long long)N + n);
            }
        }
    }
}

// ---------------- launcher ----------------

extern "C" void kernel_launch(void* const* d_in, const int* in_sizes, int n_in,
                              void* d_out, int out_size, void* d_ws, size_t ws_size,
                              hipStream_t stream) {
    (void)n_in; (void)out_size;
    const float* x  = (const float*)d_in[0];
    const float* w1 = (const float*)d_in[1];
    const float* w2 = (const float*)d_in[2];
    float* out = (float*)d_out;

    const int D = 2048, H = 8192;
    const long long M = (long long)in_sizes[0] / D;  // 8192

    char* base = (char*)d_ws;
    size_t off = 0;
    auto alloc = [&](size_t bytes) -> char* {
        char* r = base + off;
        off = (off + bytes + 255) & ~(size_t)255;
        return r;
    };

    const bool fullM = ws_size >= (size_t)236 * 1024 * 1024;
    const long long MC = fullM ? M : M / 2;

    float* part = (float*)alloc(4096 * 4);
    float* scales = (float*)alloc(256);
    float* dqx = (float*)alloc((size_t)M * 4);
    float* dqh = (float*)alloc((size_t)M * 4);
    signed char* wq = (signed char*)alloc((size_t)H * D);      // w1 then w2 overlay
    signed char* xq = (signed char*)alloc((size_t)M * D);
    signed char* hq = (signed char*)alloc((size_t)M * H);      // int8 h (pi layout)
    unsigned short* hf = (unsigned short*)alloc((size_t)MC * H * 2);  // fp16 h (pi)

    const int nw4 = H * D / 4;
    abssum2<<<4096, TPB, 0, stream>>>(w1, w2, nw4, part);
    finalize_scales<<<1, TPB, 0, stream>>>(part, scales, 1.0f / (float)(H * D));
    quant_w_i8<<<2048, TPB, 0, stream>>>(w1, wq, scales, 0, nw4);
    quant_x_i8<2><<<(int)M, TPB, 0, stream>>>(x, xq, dqx, D);

    if (fullM) {
        gemm1p<<<dim3(32, 8), 512, 0, stream>>>(xq, wq, hf, H, D, dqx, scales, 4);
        quant_h_i8<4><<<(int)M, TPB, 0, stream>>>(hf, hq, dqh, H);
    } else {
        for (int g = 0; g < 2; ++g) {
            const long long m0 = g * MC;
            gemm1p<<<dim3(32, 8), 512, 0, stream>>>(
                xq + m0 * D, wq, hf, H, D, dqx + m0, scales, 2);
            quant_h_i8<4><<<(int)MC, TPB, 0, stream>>>(hf, hq + m0 * H, dqh + m0, H);
        }
    }

    // w2 ternarized with the matching pi K-permutation
    quant_w2_i8perm<<<2048, TPB, 0, stream>>>(w2, wq, scales, nw4);

    gemm2k32<<<dim3(D / 256, (int)(M / 256)), 512, 0, stream>>>(
        hq, wq, out, D, H, dqh, scales);
}

// Round 16
// 348.666 us; speedup vs baseline: 1.0528x; 1.0528x over previous
//
#include <hip/hip_runtime.h>
#include <hip/hip_bf16.h>
#include <hip/hip_fp16.h>
#include <stdint.h>

#define TPB 256
#define EPSF 1e-5f

using i32x4 = __attribute__((ext_vector_type(4))) int;

// ---------------- helpers ----------------

__device__ __forceinline__ void gload16(const void* g, void* l) {
    __builtin_amdgcn_global_load_lds(
        (__attribute__((address_space(1))) void*)g,
        (__attribute__((address_space(3))) void*)l,
        16, 0, 0);
}

__device__ __forceinline__ float wave_reduce_sum(float v) {
#pragma unroll
    for (int off = 32; off > 0; off >>= 1) v += __shfl_down(v, off, 64);
    return v;
}

__device__ __forceinline__ float wave_reduce_max(float v) {
#pragma unroll
    for (int off = 32; off > 0; off >>= 1) v = fmaxf(v, __shfl_down(v, off, 64));
    return v;
}

__device__ __forceinline__ int q8(float f, float scale, float lo, float hi) {
    return (int)fminf(fmaxf(rintf(f * scale), lo), hi);
}

// fast GELU: x * sigmoid(2*u), u = sqrt(2/pi)*(x + 0.044715 x^3)
__device__ __forceinline__ float gelu_fast(float x) {
    float x2 = x * x;
    float u = x * (0.7978845608f + 0.0356774081f * x2);
    float e = exp2f(u * -2.8853900817779268f);   // exp(-2u)
    return x * __builtin_amdgcn_rcpf(1.0f + e);
}

// ---------------- scale reduction (deterministic two-pass) ----------------

__global__ void abssum2(const float* __restrict__ w1, const float* __restrict__ w2,
                        int n4, float* __restrict__ part) {
    const bool second = blockIdx.x >= 2048;
    const float4* w4 = (const float4*)(second ? w2 : w1);
    const int b = blockIdx.x & 2047;
    float acc = 0.f;
    for (int i = b * TPB + threadIdx.x; i < n4; i += 2048 * TPB) {
        float4 v = w4[i];
        acc += fabsf(v.x) + fabsf(v.y) + fabsf(v.z) + fabsf(v.w);
    }
    acc = wave_reduce_sum(acc);
    __shared__ float sh[4];
    if ((threadIdx.x & 63) == 0) sh[threadIdx.x >> 6] = acc;
    __syncthreads();
    if (threadIdx.x == 0) part[blockIdx.x] = sh[0] + sh[1] + sh[2] + sh[3];
}

__global__ void finalize_scales(const float* __restrict__ part,
                                float* __restrict__ scales, float inv_n) {
    float a = 0.f, b = 0.f;
    for (int i = threadIdx.x; i < 2048; i += TPB) { a += part[i]; b += part[i + 2048]; }
    a = wave_reduce_sum(a);
    b = wave_reduce_sum(b);
    __shared__ float sa[4], sb[4];
    if ((threadIdx.x & 63) == 0) { sa[threadIdx.x >> 6] = a; sb[threadIdx.x >> 6] = b; }
    __syncthreads();
    if (threadIdx.x == 0) {
        scales[0] = fmaxf((sa[0] + sa[1] + sa[2] + sa[3]) * inv_n, EPSF);
        scales[1] = fmaxf((sb[0] + sb[1] + sb[2] + sb[3]) * inv_n, EPSF);
    }
}

// ---------------- weight ternarization -> int8 (natural K order, for w1) -----

__global__ void quant_w_i8(const float* __restrict__ w,
                           signed char* __restrict__ wq,
                           const float* __restrict__ scales, int sidx, int n4) {
    const float inv = 1.0f / scales[sidx];
    const float4* w4 = (const float4*)w;
    unsigned* oq = (unsigned*)wq;
    for (int i = blockIdx.x * TPB + threadIdx.x; i < n4; i += gridDim.x * TPB) {
        float4 v = w4[i];
        unsigned p = ((unsigned)(q8(v.x, inv, -1.f, 1.f) & 0xff)) |
                     ((unsigned)(q8(v.y, inv, -1.f, 1.f) & 0xff) << 8) |
                     ((unsigned)(q8(v.z, inv, -1.f, 1.f) & 0xff) << 16) |
                     ((unsigned)(q8(v.w, inv, -1.f, 1.f) & 0xff) << 24);
        oq[i] = p;
    }
}

// ---------------- w2 ternarization with within-64 K-permutation -------------
// pi(c) = 4*(c&15) + ((c>>4)&3) within each 64-aligned K group. h/hq use the
// same pi, so GEMM2's MFMA pairs identical logical k in matching byte slots.

__global__ void quant_w2_i8perm(const float* __restrict__ w,
                                signed char* __restrict__ wq,
                                const float* __restrict__ scales, int n4) {
    const float inv = 1.0f / scales[1];
    const float4* w4 = (const float4*)w;
    unsigned* oq = (unsigned*)wq;
    const int t = threadIdx.x;
    const int g = t & 15;
    const int srcbase = (t & ~15);
    for (int i = blockIdx.x * TPB + t; i < n4; i += gridDim.x * TPB) {
        float4 v = w4[i];
        unsigned p = ((unsigned)(q8(v.x, inv, -1.f, 1.f) & 0xff)) |
                     ((unsigned)(q8(v.y, inv, -1.f, 1.f) & 0xff) << 8) |
                     ((unsigned)(q8(v.z, inv, -1.f, 1.f) & 0xff) << 16) |
                     ((unsigned)(q8(v.w, inv, -1.f, 1.f) & 0xff) << 24);
        unsigned out = 0;
#pragma unroll
        for (int j = 0; j < 4; ++j) {
            unsigned pj = (unsigned)__shfl((int)p, srcbase + 4 * j + (g >> 2), 64);
            out |= ((pj >> ((g & 3) * 8)) & 0xffu) << (8 * j);
        }
        oq[i] = out;
    }
}

// ---------------- per-row activation quant: fp32 -> int8 ----------------

template <int NF4>
__global__ void quant_x_i8(const float* __restrict__ in,
                           signed char* __restrict__ outq,
                           float* __restrict__ dq, int cols) {
    const long long row = blockIdx.x;
    const float4* r4 = (const float4*)(in + row * (long long)cols);
    float4 v[NF4];
    float mx = 0.f;
#pragma unroll
    for (int j = 0; j < NF4; ++j) {
        v[j] = r4[threadIdx.x + TPB * j];
        mx = fmaxf(mx, fmaxf(fmaxf(fabsf(v[j].x), fabsf(v[j].y)),
                             fmaxf(fabsf(v[j].z), fabsf(v[j].w))));
    }
    mx = wave_reduce_max(mx);
    __shared__ float sh[4];
    __shared__ float res;
    if ((threadIdx.x & 63) == 0) sh[threadIdx.x >> 6] = mx;
    __syncthreads();
    if (threadIdx.x == 0) res = fmaxf(fmaxf(sh[0], sh[1]), fmaxf(sh[2], sh[3]));
    __syncthreads();
    const float clipped = fmaxf(res, EPSF);
    const float scale = 127.f / clipped;
    if (threadIdx.x == 0) dq[row] = clipped / 127.f;
    unsigned* oq = (unsigned*)(outq + row * (long long)cols);
#pragma unroll
    for (int j = 0; j < NF4; ++j) {
        unsigned p = ((unsigned)(q8(v[j].x, scale, -128.f, 127.f) & 0xff)) |
                     ((unsigned)(q8(v[j].y, scale, -128.f, 127.f) & 0xff) << 8) |
                     ((unsigned)(q8(v[j].z, scale, -128.f, 127.f) & 0xff) << 16) |
                     ((unsigned)(q8(v[j].w, scale, -128.f, 127.f) & 0xff) << 24);
        oq[threadIdx.x + TPB * j] = p;
    }
}

// ---------------- per-row quant: fp16 (pre-gelu) -> gelu -> int8 ------------

template <int NJ>
__global__ void quant_h_i8(const unsigned short* __restrict__ h,
                           signed char* __restrict__ outq,
                           float* __restrict__ dq, int cols) {
    const long long row = blockIdx.x;
    const unsigned short* rp = h + row * (long long)cols;
    float g[NJ * 8];
    float mx = 0.f;
#pragma unroll
    for (int j = 0; j < NJ; ++j) {
        uint4 v = *(const uint4*)(rp + (threadIdx.x + TPB * j) * 8);
        const unsigned* u = (const unsigned*)&v;
#pragma unroll
        for (int e = 0; e < 4; ++e) {
            float2 f2 = __half22float2(*(const __half2*)&u[e]);
            float g0 = gelu_fast(f2.x);
            float g1 = gelu_fast(f2.y);
            g[j * 8 + 2 * e] = g0;
            g[j * 8 + 2 * e + 1] = g1;
            mx = fmaxf(mx, fmaxf(fabsf(g0), fabsf(g1)));
        }
    }
    mx = wave_reduce_max(mx);
    __shared__ float sh[4];
    __shared__ float res;
    if ((threadIdx.x & 63) == 0) sh[threadIdx.x >> 6] = mx;
    __syncthreads();
    if (threadIdx.x == 0) res = fmaxf(fmaxf(sh[0], sh[1]), fmaxf(sh[2], sh[3]));
    __syncthreads();
    const float clipped = fmaxf(res, EPSF);
    const float scale = 127.f / clipped;
    if (threadIdx.x == 0) dq[row] = clipped / 127.f;
    uint2* oq = (uint2*)(outq + row * (long long)cols);
#pragma unroll
    for (int j = 0; j < NJ; ++j) {
        unsigned o[2] = {0, 0};
#pragma unroll
        for (int e = 0; e < 8; ++e) {
            unsigned b = (unsigned)(q8(g[j * 8 + e], scale, -128.f, 127.f) & 0xff);
            o[e >> 2] |= b << ((e & 3) * 8);
        }
        oq[threadIdx.x + TPB * j] = *(uint2*)o;
    }
}

// ---------------- shared GEMM pieces ----------------

__device__ __forceinline__ void stage_half(const char* Xb, long long rowB, int prow,
                                           int tk, char* dst, int tid, int cbs) {
    const long long gc = (long long)tk * 128 + cbs;
    const int r = tid >> 3;
    gload16(Xb + (long long)(prow + r) * rowB + gc, dst + tid * 16);
    gload16(Xb + (long long)(prow + 64 + r) * rowB + gc, dst + 8192 + tid * 16);
}

#define QUAD(MB, NB)                                                            \
    _Pragma("unroll") for (int mi = 0; mi < 4; ++mi)                            \
    _Pragma("unroll") for (int ni = 0; ni < 2; ++ni)                            \
    _Pragma("unroll") for (int ks = 0; ks < 2; ++ks)                            \
        acc[(MB)*4 + mi][(NB)*2 + ni] = __builtin_amdgcn_mfma_i32_16x16x64_i8(  \
            aq[mi][ks], bq[(NB)*2 + ni][ks], acc[(MB)*4 + mi][(NB)*2 + ni], 0, 0, 0);

#define READ_A(BUF, base_mi)                                                    \
    _Pragma("unroll") for (int mi = 0; mi < 4; ++mi) {                          \
        const char* p = (BUF) + aoff + ((mi + (base_mi)) * 16 + l15) * 128;     \
        aq[mi][0] = *(const i32x4*)(p + acb0);                                  \
        aq[mi][1] = *(const i32x4*)(p + acb1);                                  \
    }
#define READ_B(BUF, n0i, n1i)                                                   \
    _Pragma("unroll") for (int ni = (n0i); ni < (n1i); ++ni) {                  \
        const char* p = (BUF) + boff + (ni * 16 + l15) * 128;                   \
        bq[ni][0] = *(const i32x4*)(p + acb0);                                  \
        bq[ni][1] = *(const i32x4*)(p + acb1);                                  \
    }

#define LGKM(N) do { asm volatile("s_waitcnt lgkmcnt(" #N ")" ::: "memory");    \
                     __builtin_amdgcn_sched_barrier(0); } while (0)

// split epilogue for gemm1p: rows [MLO,MHI), NO gelu, pi-packed 8B stores
#define EMIT1(MLO, MHI, M0V)                                                    \
    _Pragma("unroll") for (int mi = (MLO); mi < (MHI); ++mi) {                  \
        _Pragma("unroll") for (int r = 0; r < 4; ++r) {                         \
            const long long m = (M0V) + wr * 128 + mi * 16 + l4 * 4 + r;        \
            const float f = dq[m] * s;                                          \
            __half2 lo = __floats2half2_rn((float)acc[mi][0][r] * f,            \
                                           (float)acc[mi][1][r] * f);           \
            __half2 hi = __floats2half2_rn((float)acc[mi][2][r] * f,            \
                                           (float)acc[mi][3][r] * f);           \
            uint2 pk;                                                           \
            pk.x = *(const unsigned*)&lo;                                       \
            pk.y = *(const unsigned*)&hi;                                       \
            *(uint2*)(C + m * (long long)N + n0 + wc * 64 + l15 * 4) = pk;      \
            acc[mi][0][r] = 0; acc[mi][1][r] = 0;                               \
            acc[mi][2][r] = 0; acc[mi][3][r] = 0;                               \
        }                                                                       \
    }

// ---------------- persistent GEMM1: x@w1^T -> fp16 h' (pi layout) -----------
// R14 exact (16x16x64, read-ahead skeleton, thin epilogue).

__global__ __launch_bounds__(512, 2) void gemm1p(
    const signed char* __restrict__ A, const signed char* __restrict__ B,
    unsigned short* __restrict__ C, int N, int K,
    const float* __restrict__ dq, const float* __restrict__ scales, int ntile) {
    __shared__ __align__(16) char lds[131072];

    const int tid = threadIdx.x;
    const int lane = tid & 63;
    const int wid = tid >> 6;
    const int wr = wid >> 2;
    const int wc = wid & 3;

    const unsigned orig = blockIdx.y * gridDim.x + blockIdx.x;
    const unsigned xk = orig & 7, j = orig >> 3;
    const unsigned bx = xk * 4 + (j & 3);
    const unsigned byg = j >> 2;

    const int n0 = (int)bx * 256;
    const long long rb = (long long)K;
    const char* Ab = (const char*)A;
    const char* Bb = (const char*)B;

    const int NTT = ntile << 4;

    const int cbs = (((tid & 7) ^ ((tid >> 3) & 7)) << 4);
    const int l15 = lane & 15, l4 = lane >> 4;
    const int swz = (lane & 7) << 4;
    const int acb0 = (l4 * 16) ^ swz;
    const int acb1 = (64 + l4 * 16) ^ swz;
    const int aoff = wr * 16384;
    const int boff = 32768 + (wc >> 1) * 16384 + (wc & 1) * 8192;

    i32x4 acc[8][4] = {};
    i32x4 aq[4][2], bq[4][2];

    auto mrow = [&](int v) -> int { return ((int)byg * ntile + (v >> 4)) * 256; };

    stage_half(Bb, rb, n0, 0, lds + 32768, tid, cbs);
    stage_half(Bb, rb, n0 + 128, 0, lds + 32768 + 16384, tid, cbs);
    stage_half(Ab, rb, mrow(0), 0, lds + 0, tid, cbs);
    stage_half(Ab, rb, mrow(0) + 128, 0, lds + 16384, tid, cbs);
    stage_half(Bb, rb, n0, 1, lds + 65536 + 32768, tid, cbs);
    stage_half(Bb, rb, n0 + 128, 1, lds + 65536 + 32768 + 16384, tid, cbs);
    stage_half(Ab, rb, mrow(1), 1, lds + 65536, tid, cbs);
    asm volatile("s_waitcnt vmcnt(6)" ::: "memory");
    __builtin_amdgcn_sched_barrier(0);
    __builtin_amdgcn_s_barrier();
    READ_A(lds, 0);
    READ_B(lds, 0, 2);

    const float s = scales[0];

    for (int vt = 0; vt < NTT; ++vt) {
        char* cur = lds + ((vt & 1) << 16);
        char* nxt = lds + (((vt + 1) & 1) << 16);
        const bool s1 = (vt + 1) < NTT;
        const bool s2 = (vt + 2) < NTT;
        const int kk = vt & 15;
        const int k1 = (vt + 1) & 15;
        const int k2 = (vt + 2) & 15;

        // P0
        if (s1) stage_half(Ab, rb, mrow(vt + 1) + 128, k1, nxt + 16384, tid, cbs);
        READ_B(cur, 2, 4);
        if (kk == 0 && vt > 0) { EMIT1(4, 8, mrow(vt - 1)); }
        __builtin_amdgcn_s_barrier();
        LGKM(4);
        __builtin_amdgcn_s_setprio(1);
        QUAD(0, 0);
        __builtin_amdgcn_s_setprio(0);

        // P1
        __builtin_amdgcn_s_barrier();
        LGKM(0);
        __builtin_amdgcn_s_setprio(1);
        QUAD(0, 1);
        __builtin_amdgcn_s_setprio(0);

        // P2
        if (s2) {
            stage_half(Bb, rb, n0, k2, cur + 32768, tid, cbs);
            stage_half(Bb, rb, n0 + 128, k2, cur + 32768 + 16384, tid, cbs);
        }
        READ_A(cur, 4);
        if (kk == 15) { EMIT1(0, 4, mrow(vt)); }
        __builtin_amdgcn_s_barrier();
        LGKM(0);
        __builtin_amdgcn_s_setprio(1);
        QUAD(1, 0);
        __builtin_amdgcn_s_setprio(0);

        // P3
        if (s2) { asm volatile("s_waitcnt vmcnt(4)" ::: "memory"); }
        else    { asm volatile("s_waitcnt vmcnt(0)" ::: "memory"); }
        __builtin_amdgcn_sched_barrier(0);
        __builtin_amdgcn_s_barrier();
        if (s2) stage_half(Ab, rb, mrow(vt + 2), k2, cur, tid, cbs);
        __builtin_amdgcn_s_setprio(1);
        QUAD(1, 1);
        __builtin_amdgcn_s_setprio(0);
        if (s1) {
            READ_A(nxt, 0);
            READ_B(nxt, 0, 2);
        }
    }

    { EMIT1(4, 8, mrow(NTT - 1)); }
}

// ---------------- 256x256 read-ahead i8 GEMM2 (R9/R14 exact, 16x16x64) ------

#define EMIT2(MLO, MHI)                                                         \
    _Pragma("unroll") for (int mi = (MLO); mi < (MHI); ++mi) {                  \
        _Pragma("unroll") for (int r = 0; r < 4; ++r) {                         \
            const long long m = M0 + wr * 128 + mi * 16 + l4 * 4 + r;           \
            const float f = dq[m] * s;                                          \
            _Pragma("unroll") for (int ni = 0; ni < 4; ++ni) {                  \
                const long long n = N0 + wc * 64 + ni * 16 + l15;               \
                __builtin_nontemporal_store(                                    \
                    (float)acc[mi][ni][r] * f, C + m * (long long)N + n);       \
            }                                                                   \
        }                                                                       \
    }

__global__ __launch_bounds__(512, 2) void gemm2k(
    const signed char* __restrict__ A, const signed char* __restrict__ B,
    float* __restrict__ C, int N, int K,
    const float* __restrict__ dq, const float* __restrict__ scales) {
    __shared__ __align__(16) char lds[131072];

    const int tid = threadIdx.x;
    const int lane = tid & 63;
    const int wid = tid >> 6;
    const int wr = wid >> 2;
    const int wc = wid & 3;

    const unsigned gx = gridDim.x;
    unsigned lin = blockIdx.y * gx + blockIdx.x;
    const unsigned qq = (gx * gridDim.y) >> 3;
    lin = (lin & 7) * qq + (lin >> 3);
    const unsigned bx = lin % gx;
    const unsigned by = lin / gx;

    const long long M0 = (long long)by * 256;
    const long long N0 = (long long)bx * 256;
    const long long rb = (long long)K;
    const char* Ab = (const char*)A + M0 * rb;
    const char* Bb = (const char*)B + N0 * rb;
    const int nt = K >> 7;

    const int cbs = (((tid & 7) ^ ((tid >> 3) & 7)) << 4);
    const int l15 = lane & 15, l4 = lane >> 4;
    const int swz = (lane & 7) << 4;
    const int acb0 = (l4 * 16) ^ swz;
    const int acb1 = (64 + l4 * 16) ^ swz;
    const int aoff = wr * 16384;
    const int boff = 32768 + (wc >> 1) * 16384 + (wc & 1) * 8192;

    i32x4 acc[8][4] = {};
    i32x4 aq[4][2], bq[4][2];

    stage_half(Bb, rb, 0,   0, lds + 32768,         tid, cbs);
    stage_half(Bb, rb, 128, 0, lds + 32768 + 16384, tid, cbs);
    stage_half(Ab, rb, 0,   0, lds + 0,             tid, cbs);
    stage_half(Ab, rb, 128, 0, lds + 16384,         tid, cbs);
    stage_half(Bb, rb, 0,   1, lds + 65536 + 32768,         tid, cbs);
    stage_half(Bb, rb, 128, 1, lds + 65536 + 32768 + 16384, tid, cbs);
    stage_half(Ab, rb, 0,   1, lds + 65536,                 tid, cbs);
    asm volatile("s_waitcnt vmcnt(6)" ::: "memory");
    __builtin_amdgcn_sched_barrier(0);
    __builtin_amdgcn_s_barrier();
    READ_A(lds, 0);
    READ_B(lds, 0, 2);

    const float s = scales[1];

    for (int t = 0; t < nt; ++t) {
        char* cur = lds + ((t & 1) << 16);
        char* nxt = lds + (((t + 1) & 1) << 16);
        const bool s1 = (t + 1) < nt;
        const bool s2 = (t + 2) < nt;

        // P0
        if (s1) stage_half(Ab, rb, 128, t + 1, nxt + 16384, tid, cbs);
        READ_B(cur, 2, 4);
        __builtin_amdgcn_s_barrier();
        LGKM(4);
        __builtin_amdgcn_s_setprio(1);
        QUAD(0, 0);
        __builtin_amdgcn_s_setprio(0);

        // P1
        __builtin_amdgcn_s_barrier();
        LGKM(0);
        __builtin_amdgcn_s_setprio(1);
        QUAD(0, 1);
        __builtin_amdgcn_s_setprio(0);

        // P2
        if (s2) {
            stage_half(Bb, rb, 0, t + 2, cur + 32768, tid, cbs);
            stage_half(Bb, rb, 128, t + 2, cur + 32768 + 16384, tid, cbs);
        }
        READ_A(cur, 4);
        if (t == nt - 1) { EMIT2(0, 4); }
        __builtin_amdgcn_s_barrier();
        LGKM(0);
        __builtin_amdgcn_s_setprio(1);
        QUAD(1, 0);
        __builtin_amdgcn_s_setprio(0);

        // P3
        if (s2) { asm volatile("s_waitcnt vmcnt(4)" ::: "memory"); }
        else    { asm volatile("s_waitcnt vmcnt(0)" ::: "memory"); }
        __builtin_amdgcn_sched_barrier(0);
        __builtin_amdgcn_s_barrier();
        if (s2) stage_half(Ab, rb, 0, t + 2, cur, tid, cbs);
        __builtin_amdgcn_s_setprio(1);
        QUAD(1, 1);
        __builtin_amdgcn_s_setprio(0);
        if (s1) {
            READ_A(nxt, 0);
            READ_B(nxt, 0, 2);
        }
    }

    { EMIT2(4, 8); }
}

// ---------------- launcher ----------------

extern "C" void kernel_launch(void* const* d_in, const int* in_sizes, int n_in,
                              void* d_out, int out_size, void* d_ws, size_t ws_size,
                              hipStream_t stream) {
    (void)n_in; (void)out_size;
    const float* x  = (const float*)d_in[0];
    const float* w1 = (const float*)d_in[1];
    const float* w2 = (const float*)d_in[2];
    float* out = (float*)d_out;

    const int D = 2048, H = 8192;
    const long long M = (long long)in_sizes[0] / D;  // 8192

    char* base = (char*)d_ws;
    size_t off = 0;
    auto alloc = [&](size_t bytes) -> char* {
        char* r = base + off;
        off = (off + bytes + 255) & ~(size_t)255;
        return r;
    };

    const bool fullM = ws_size >= (size_t)236 * 1024 * 1024;
    const long long MC = fullM ? M : M / 2;

    float* part = (float*)alloc(4096 * 4);
    float* scales = (float*)alloc(256);
    float* dqx = (float*)alloc((size_t)M * 4);
    float* dqh = (float*)alloc((size_t)M * 4);
    signed char* wq = (signed char*)alloc((size_t)H * D);      // w1 then w2 overlay
    signed char* xq = (signed char*)alloc((size_t)M * D);
    signed char* hq = (signed char*)alloc((size_t)M * H);      // int8 h (pi layout)
    unsigned short* hf = (unsigned short*)alloc((size_t)MC * H * 2);  // fp16 h (pi)

    const int nw4 = H * D / 4;
    abssum2<<<4096, TPB, 0, stream>>>(w1, w2, nw4, part);
    finalize_scales<<<1, TPB, 0, stream>>>(part, scales, 1.0f / (float)(H * D));
    quant_w_i8<<<2048, TPB, 0, stream>>>(w1, wq, scales, 0, nw4);
    quant_x_i8<2><<<(int)M, TPB, 0, stream>>>(x, xq, dqx, D);

    if (fullM) {
        gemm1p<<<dim3(32, 8), 512, 0, stream>>>(xq, wq, hf, H, D, dqx, scales, 4);
        quant_h_i8<4><<<(int)M, TPB, 0, stream>>>(hf, hq, dqh, H);
    } else {
        for (int g = 0; g < 2; ++g) {
            const long long m0 = g * MC;
            gemm1p<<<dim3(32, 8), 512, 0, stream>>>(
                xq + m0 * D, wq, hf, H, D, dqx + m0, scales, 2);
            quant_h_i8<4><<<(int)MC, TPB, 0, stream>>>(hf, hq + m0 * H, dqh + m0, H);
        }
    }

    // w2 ternarized with the matching pi K-permutation
    quant_w2_i8perm<<<2048, TPB, 0, stream>>>(w2, wq, scales, nw4);

    gemm2k<<<dim3(D / 256, (int)(M / 256)), 512, 0, stream>>>(
        hq, wq, out, D, H, dqh, scales);
}